// Round 9
// baseline (154.174 us; speedup 1.0000x reference)
//
#include <hip/hip_runtime.h>

typedef __attribute__((ext_vector_type(8)))  _Float16 f16x8;
typedef __attribute__((ext_vector_type(4)))  float    f32x4;
typedef __attribute__((ext_vector_type(16))) float    f32x16;
typedef __attribute__((ext_vector_type(4)))  int      i32x4;

#define IN_F   4096
#define OUT_F  4096
#define NGRP   32
#define NKT    64          /* K-tiles of 64 */

#define GLOAD16(gsrc, ldst)                                                   \
    __builtin_amdgcn_global_load_lds(                                         \
        (const __attribute__((address_space(1))) unsigned int*)(gsrc),        \
        (__attribute__((address_space(3))) unsigned int*)(ldst), 16, 0, 0)

#define CFENCE  asm volatile("" ::: "memory")
#define BARRIER do { CFENCE; __builtin_amdgcn_s_barrier(); CFENCE; } while (0)
#define VMW6    asm volatile("s_waitcnt vmcnt(6)" ::: "memory")

// ---------------- fused prepass: X fp32->f16 and int4 dequant->f16 ----------
__global__ __launch_bounds__(256)
void prep(const float* __restrict__ X, const int* __restrict__ QW,
          const float* __restrict__ S, _Float16* __restrict__ XF,
          _Float16* __restrict__ WF) {
    if (blockIdx.x < 8192) {
        size_t i = ((size_t)blockIdx.x * 256 + threadIdx.x) * 8;
        f32x4 a = *(const f32x4*)(X + i);
        f32x4 b = *(const f32x4*)(X + i + 4);
        f16x8 h;
        h[0] = (_Float16)a[0]; h[1] = (_Float16)a[1];
        h[2] = (_Float16)a[2]; h[3] = (_Float16)a[3];
        h[4] = (_Float16)b[0]; h[5] = (_Float16)b[1];
        h[6] = (_Float16)b[2]; h[7] = (_Float16)b[3];
        *(f16x8*)(XF + i) = h;
    } else {
        size_t t  = ((size_t)blockIdx.x - 8192) * 256 + threadIdx.x;
        size_t jj = t * 4;                   // int32 index; 2048 per row
        size_t o  = jj >> 11;
        size_t jr = jj & 2047;
        const float s = S[o * NGRP + (jr >> 6)];   // group const across 4 int32
        i32x4 q = *(const i32x4*)(QW + jj);
        f16x8 h;
#pragma unroll
        for (int j = 0; j < 4; ++j) {
            const int v = q[j];
            h[2 * j]     = (_Float16)((float)(((v >> 4) & 15) - 8) * s);
            h[2 * j + 1] = (_Float16)((float)((v & 15) - 8) * s);
        }
        *(f16x8*)(WF + jj * 2) = h;
    }
}

// ---------------- main GEMM: 256^2, BK=64, 8-phase, 32x32x16 MFMA -----------
// Round-7 skeleton (stage plan, VMW6@P3/P7-end, 1 barrier/phase, setprio)
// with the MFMA shape switched 16x16x32 -> 32x32x16: ~15% fewer MFMA-pipe
// cycles (2495 vs 2075 TF ceiling), half the MFMA instruction count, same
// LDS traffic, same register footprint.
// Frag maps: A/B row(col)=lane&31, k=(lane>>5)*8+j; C/D col=lane&31,
// row=(reg&3)+8*(reg>>2)+4*(lane>>5) [m74/m101].
__global__ __launch_bounds__(512, 2)
void gemm8p(const _Float16* __restrict__ A,
            const _Float16* __restrict__ B,
            float*          __restrict__ C)
{
    extern __shared__ char LDSc[];
    char* const ldsA = LDSc;
    char* const ldsB = LDSc + 65536;

    const int tid  = threadIdx.x;
    const int lane = tid & 63;
    const int wid  = tid >> 6;
    const int wm   = wid >> 2;          // 0..1
    const int wn   = wid & 3;           // 0..3

    const int bid = blockIdx.x;         // 256 blocks (16x16 tiles), %8==0
    const int swz = (bid & 7) * 32 + (bid >> 3);
    const int bm0 = (swz >> 4) * 256;
    const int bn0 = (swz & 15) * 256;

    // staging source: thread covers rows r0 and r0+64 of a half-tile,
    // 16 B at swizzled byte-col cs (involution: src-perm == read-perm)
    const int r0 = tid >> 3;                                // 0..63
    const int cs = ((tid & 7) * 16) ^ ((r0 & 7) << 4);      // 0..127
    const _Float16* Asrc = A + (size_t)(bm0 + r0) * IN_F + (cs >> 1);
    const _Float16* Bsrc = B + (size_t)(bn0 + r0) * IN_F + (cs >> 1);
    const int dstoff = wid * 1024;                          // wave-uniform

    // frag-read offsets (swizzled): row-in-half has row&7 == lane&7
    const int lane31 = lane & 31;
    const int hi     = lane >> 5;                    // k-half select
    const int swr    = (lane & 7) << 4;
    int cks[4];                                      // byte col per k-step
#pragma unroll
    for (int ks = 0; ks < 4; ++ks) cks[ks] = (ks * 32 + hi * 16) ^ swr;
    int rA2off[2], rB2off;
#pragma unroll
    for (int mm = 0; mm < 2; ++mm) rA2off[mm] = (wm * 64 + mm * 32 + lane31) * 128;
    rB2off = (wn * 32 + lane31) * 128;

    f16x8 afr[2][4], blo[4], bhi[4];
    f32x16 acc[4][2];                                // [qm*2+mm2][qn]
#pragma unroll
    for (int m = 0; m < 4; ++m)
#pragma unroll
        for (int n = 0; n < 2; ++n) acc[m][n] = (f32x16)0.0f;

#define STAGE_A(HALF, KT, BUF) do {                                           \
        const _Float16* s_ = Asrc + (size_t)(HALF) * 128 * IN_F + (KT) * 64;  \
        char* d_ = ldsA + ((BUF) * 2 + (HALF)) * 16384 + dstoff;              \
        GLOAD16(s_, d_);                                                      \
        GLOAD16(s_ + (size_t)64 * IN_F, d_ + 8192); } while (0)

#define STAGE_B(HALF, KT, BUF) do {                                           \
        const _Float16* s_ = Bsrc + (size_t)(HALF) * 128 * IN_F + (KT) * 64;  \
        char* d_ = ldsB + ((BUF) * 2 + (HALF)) * 16384 + dstoff;              \
        GLOAD16(s_, d_);                                                      \
        GLOAD16(s_ + (size_t)64 * IN_F, d_ + 8192); } while (0)

#define RD_A(BUF, QM) do { char* ab_ = ldsA + ((BUF) * 2 + (QM)) * 16384;     \
        _Pragma("unroll") for (int mm = 0; mm < 2; ++mm)                      \
        _Pragma("unroll") for (int ks = 0; ks < 4; ++ks)                      \
            afr[mm][ks] = *(const f16x8*)(ab_ + rA2off[mm] + cks[ks]);        \
        } while (0)

#define RD_B(BUF, QN, DST) do { char* bb_ = ldsB + ((BUF) * 2 + (QN)) * 16384;\
        _Pragma("unroll") for (int ks = 0; ks < 4; ++ks)                      \
            DST[ks] = *(const f16x8*)(bb_ + rB2off + cks[ks]);                \
        } while (0)

#define MFMA_Q(QM, QN, BQ)                                                    \
        __builtin_amdgcn_s_setprio(1);                                        \
        _Pragma("unroll") for (int mm = 0; mm < 2; ++mm)                      \
        _Pragma("unroll") for (int ks = 0; ks < 4; ++ks)                      \
            acc[(QM)*2+mm][(QN)] =                                            \
                __builtin_amdgcn_mfma_f32_32x32x16_f16(                       \
                    afr[mm][ks], BQ[ks], acc[(QM)*2+mm][(QN)], 0, 0, 0);      \
        __builtin_amdgcn_s_setprio(0);

    // prologue: K0 full -> buf0, K1 {A0,B0,B1} -> buf1 (7 stages, 14 loads).
    // vmcnt(6) retires the oldest 4 stages = buf0/K0; barrier publishes.
    STAGE_A(0, 0, 0); STAGE_B(0, 0, 0); STAGE_B(1, 0, 0); STAGE_A(1, 0, 0);
    STAGE_A(0, 1, 1); STAGE_B(0, 1, 1); STAGE_B(1, 1, 1);
    VMW6; BARRIER;

    for (int t = 0; t < NKT; t += 2) {
        const int k2 = (t + 2) & 63;   // t=62 -> dead restage of K0/K1
        const int k3 = (t + 3) & 63;
        // ---- P0 ----
        RD_A(0, 0); RD_B(0, 0, blo); STAGE_A(1, t + 1, 1);
        MFMA_Q(0, 0, blo); BARRIER;
        // ---- P1 ----
        RD_B(0, 1, bhi); STAGE_A(0, k2, 0);
        MFMA_Q(0, 1, bhi); BARRIER;
        // ---- P2 ----
        RD_A(0, 1); STAGE_B(0, k2, 0);
        MFMA_Q(1, 0, blo); BARRIER;
        // ---- P3 ----  (VMW6 -> buf1 t+1 ready; this barrier publishes)
        STAGE_B(1, k2, 0);
        MFMA_Q(1, 1, bhi); VMW6; BARRIER;
        // ---- P4 ----
        RD_A(1, 0); RD_B(1, 0, blo); STAGE_A(1, k2, 0);
        MFMA_Q(0, 0, blo); BARRIER;
        // ---- P5 ----
        RD_B(1, 1, bhi); STAGE_A(0, k3, 1);
        MFMA_Q(0, 1, bhi); BARRIER;
        // ---- P6 ----
        RD_A(1, 1); STAGE_B(0, k3, 1);
        MFMA_Q(1, 0, blo); BARRIER;
        // ---- P7 ----  (VMW6 -> buf0 t+2 ready)
        STAGE_B(1, k3, 1);
        MFMA_Q(1, 1, bhi); VMW6; BARRIER;
    }
    asm volatile("s_waitcnt vmcnt(0)" ::: "memory");   // drain DMA before end

    // epilogue: 32x32 C/D map: col=lane&31, row=(reg&3)+8*(reg>>2)+4*hi
#pragma unroll
    for (int qm = 0; qm < 2; ++qm)
#pragma unroll
    for (int mm = 0; mm < 2; ++mm) {
        const int Mb = bm0 + qm * 128 + wm * 64 + mm * 32 + hi * 4;
#pragma unroll
        for (int qn = 0; qn < 2; ++qn) {
            const int Nc = bn0 + qn * 128 + wn * 32 + lane31;
            const f32x16 v = acc[qm * 2 + mm][qn];
#pragma unroll
            for (int r = 0; r < 16; ++r)
                C[(size_t)(Mb + (r & 3) + 8 * (r >> 2)) * OUT_F + Nc] = v[r];
        }
    }
#undef STAGE_A
#undef STAGE_B
#undef RD_A
#undef RD_B
#undef MFMA_Q
}

// ---------------- fallback: m97-structure GEMM (static 16 KB LDS) ----------
__global__ __launch_bounds__(256, 3)
void gemm_f16(const _Float16* __restrict__ A,
              const _Float16* __restrict__ B,
              float*          __restrict__ C)
{
    __shared__ __align__(16) _Float16 lA[128 * 32];
    __shared__ __align__(16) _Float16 lB[128 * 32];

    const int tid  = threadIdx.x;
    const int lane = tid & 63;
    const int bid = blockIdx.x;
    const int swz = (bid & 7) * 128 + (bid >> 3);
    const int bm0 = (swz >> 5) * 128;
    const int bn0 = (swz & 31) * 128;

    const int sr = tid >> 2;
    const int sc = (tid & 3) * 8;
    const _Float16* Aps = A + (size_t)(bm0 + sr) * IN_F + sc;
    const _Float16* Bps = B + (size_t)(bn0 + sr) * IN_F + sc;
    char* lAb = (char*)lA + (tid & ~63) * 16;
    char* lBb = (char*)lB + (tid & ~63) * 16;

    const int wv = tid >> 6;
    const int wr = (wv >> 1) * 64;
    const int wc = (wv & 1)  * 64;
    const int lr  = lane & 15;
    const int lkb = (lane >> 4) * 16;

    f32x4 acc[4][4];
#pragma unroll
    for (int m = 0; m < 4; ++m)
#pragma unroll
        for (int n = 0; n < 4; ++n) acc[m][n] = (f32x4)0.0f;

    for (int kt = 0; kt < 128; ++kt) {
        __syncthreads();
        {
            const _Float16* ak = Aps + kt * 32;
            const _Float16* bk = Bps + kt * 32;
            GLOAD16(ak, lAb);
            GLOAD16(ak + (size_t)64 * IN_F, lAb + 4096);
            GLOAD16(bk, lBb);
            GLOAD16(bk + (size_t)64 * IN_F, lBb + 4096);
        }
        __syncthreads();

        f16x8 a[4], b[4];
#pragma unroll
        for (int m = 0; m < 4; ++m)
            a[m] = *(const f16x8*)((const char*)lA + (wr + m * 16 + lr) * 64 + lkb);
#pragma unroll
        for (int n = 0; n < 4; ++n)
            b[n] = *(const f16x8*)((const char*)lB + (wc + n * 16 + lr) * 64 + lkb);
#pragma unroll
        for (int m = 0; m < 4; ++m)
#pragma unroll
            for (int n = 0; n < 4; ++n)
                acc[m][n] = __builtin_amdgcn_mfma_f32_16x16x32_f16(
                    a[m], b[n], acc[m][n], 0, 0, 0);
    }

    const int crow = bm0 + wr + (lane >> 4) * 4;
    const int ccol = bn0 + wc + lr;
#pragma unroll
    for (int m = 0; m < 4; ++m)
#pragma unroll
        for (int n = 0; n < 4; ++n)
#pragma unroll
            for (int r = 0; r < 4; ++r)
                C[(size_t)(crow + m * 16 + r) * OUT_F + (ccol + n * 16)]
                    = acc[m][n][r];
}

extern "C" void kernel_launch(void* const* d_in, const int* in_sizes, int n_in,
                              void* d_out, int out_size, void* d_ws, size_t ws_size,
                              hipStream_t stream) {
    (void)in_sizes; (void)n_in; (void)out_size; (void)ws_size;
    const float* x  = (const float*)d_in[0];
    const int*   qw = (const int*)d_in[1];
    const float* s  = (const float*)d_in[2];
    float*       out = (float*)d_out;

    _Float16* xf = (_Float16*)d_ws;
    _Float16* wf = xf + (size_t)OUT_F * IN_F;
    prep<<<dim3(16384), dim3(256), 0, stream>>>(x, qw, s, xf, wf);

    hipError_t e = hipFuncSetAttribute((const void*)gemm8p,
        hipFuncAttributeMaxDynamicSharedMemorySize, 131072);
    if (e == hipSuccess)
        gemm8p<<<dim3(256), dim3(512), 131072, stream>>>(xf, wf, out);
    else
        gemm_f16<<<dim3(1024), dim3(256), 0, stream>>>(xf, wf, out);
}

// Round 10
// 135.090 us; speedup vs baseline: 1.1413x; 1.1413x over previous
//
#include <hip/hip_runtime.h>

typedef __attribute__((ext_vector_type(8))) _Float16 f16x8;
typedef __attribute__((ext_vector_type(4))) float    f32x4;
typedef __attribute__((ext_vector_type(4))) int      i32x4;

#define IN_F   4096
#define OUT_F  4096
#define NGRP   32
#define NKT    64          /* K-tiles of 64 */

#define GLOAD16(gsrc, ldst)                                                   \
    __builtin_amdgcn_global_load_lds(                                         \
        (const __attribute__((address_space(1))) unsigned int*)(gsrc),        \
        (__attribute__((address_space(3))) unsigned int*)(ldst), 16, 0, 0)

#define CFENCE  asm volatile("" ::: "memory")
#define BARRIER do { CFENCE; __builtin_amdgcn_s_barrier(); CFENCE; } while (0)
#define VMW6    asm volatile("s_waitcnt vmcnt(6)" ::: "memory")

// ---------------- fused prepass: X fp32->f16 and int4 dequant->f16 ----------
__global__ __launch_bounds__(256)
void prep(const float* __restrict__ X, const int* __restrict__ QW,
          const float* __restrict__ S, _Float16* __restrict__ XF,
          _Float16* __restrict__ WF) {
    if (blockIdx.x < 8192) {
        size_t i = ((size_t)blockIdx.x * 256 + threadIdx.x) * 8;
        f32x4 a = *(const f32x4*)(X + i);
        f32x4 b = *(const f32x4*)(X + i + 4);
        f16x8 h;
        h[0] = (_Float16)a[0]; h[1] = (_Float16)a[1];
        h[2] = (_Float16)a[2]; h[3] = (_Float16)a[3];
        h[4] = (_Float16)b[0]; h[5] = (_Float16)b[1];
        h[6] = (_Float16)b[2]; h[7] = (_Float16)b[3];
        *(f16x8*)(XF + i) = h;
    } else {
        size_t t  = ((size_t)blockIdx.x - 8192) * 256 + threadIdx.x;
        size_t jj = t * 4;                   // int32 index; 2048 per row
        size_t o  = jj >> 11;
        size_t jr = jj & 2047;
        const float s = S[o * NGRP + (jr >> 6)];   // group const across 4 int32
        i32x4 q = *(const i32x4*)(QW + jj);
        f16x8 h;
#pragma unroll
        for (int j = 0; j < 4; ++j) {
            const int v = q[j];
            h[2 * j]     = (_Float16)((float)(((v >> 4) & 15) - 8) * s);
            h[2 * j + 1] = (_Float16)((float)((v & 15) - 8) * s);
        }
        *(f16x8*)(WF + jj * 2) = h;
    }
}

// ---------------- main GEMM: 256^2, BK=64, MERGED phases (2/K-tile) ---------
// Round-7 skeleton with phases merged: per K-tile, 2 phases of 2 quadrants
// (32 MFMA) each; 4 barriers per 2 K-tiles instead of 8 (less wave re-convoy).
// Stage plan (audited): PA: A1(t+1)->b1 (2 loads). PB: A0,B0,B1(t+2)->b0
// (6 loads; moved OUT of PA so no same-phase stage-vs-other-wave-read WAR).
// PC: A1(t+2)->b0. PD: A0,B0,B1(t+3)->b1. Every stage >=1 barrier after its
// region's last read. VMW6 (loads): steady outstanding 8->14 peak; VMW6 at
// PB/PD ends retires exactly the next buffer's 4 stages (8 loads), keeps
// newest 3 stages (6 loads); trailing barrier publishes cross-wave.
__global__ __launch_bounds__(512, 2)
void gemm8p(const _Float16* __restrict__ A,
            const _Float16* __restrict__ B,
            float*          __restrict__ C)
{
    extern __shared__ char LDSc[];
    char* const ldsA = LDSc;
    char* const ldsB = LDSc + 65536;

    const int tid  = threadIdx.x;
    const int lane = tid & 63;
    const int wid  = tid >> 6;
    const int wm   = wid >> 2;          // 0..1
    const int wn   = wid & 3;           // 0..3

    const int bid = blockIdx.x;         // 256 blocks (16x16 tiles), %8==0
    const int swz = (bid & 7) * 32 + (bid >> 3);
    const int bm0 = (swz >> 4) * 256;
    const int bn0 = (swz & 15) * 256;

    // staging source: thread covers rows r0 and r0+64 of a half-tile,
    // 16 B at swizzled byte-col cs (involution: src-perm == read-perm)
    const int r0 = tid >> 3;                                // 0..63
    const int cs = ((tid & 7) * 16) ^ ((r0 & 7) << 4);      // 0..127
    const _Float16* Asrc = A + (size_t)(bm0 + r0) * IN_F + (cs >> 1);
    const _Float16* Bsrc = B + (size_t)(bn0 + r0) * IN_F + (cs >> 1);
    const int dstoff = wid * 1024;                          // wave-uniform

    // frag-read offsets (swizzled)
    const int lane15 = lane & 15;
    const int swr = (lane & 7) << 4;
    const int c0 = ((lane >> 4) * 16) ^ swr;        // kk=0 byte col
    const int c1 = (64 + (lane >> 4) * 16) ^ swr;   // kk=1
    int rAoff[4], rBoff[2];
#pragma unroll
    for (int mm = 0; mm < 4; ++mm) rAoff[mm] = (wm * 64 + mm * 16 + lane15) * 128;
#pragma unroll
    for (int nn = 0; nn < 2; ++nn) rBoff[nn] = (wn * 32 + nn * 16 + lane15) * 128;

    f16x8 afr[4][2], blo[2][2], bhi[2][2];
    f32x4 acc[8][4];
#pragma unroll
    for (int m = 0; m < 8; ++m)
#pragma unroll
        for (int n = 0; n < 4; ++n) acc[m][n] = (f32x4)0.0f;

#define STAGE_A(HALF, KT, BUF) do {                                           \
        const _Float16* s_ = Asrc + (size_t)(HALF) * 128 * IN_F + (KT) * 64;  \
        char* d_ = ldsA + ((BUF) * 2 + (HALF)) * 16384 + dstoff;              \
        GLOAD16(s_, d_);                                                      \
        GLOAD16(s_ + (size_t)64 * IN_F, d_ + 8192); } while (0)

#define STAGE_B(HALF, KT, BUF) do {                                           \
        const _Float16* s_ = Bsrc + (size_t)(HALF) * 128 * IN_F + (KT) * 64;  \
        char* d_ = ldsB + ((BUF) * 2 + (HALF)) * 16384 + dstoff;              \
        GLOAD16(s_, d_);                                                      \
        GLOAD16(s_ + (size_t)64 * IN_F, d_ + 8192); } while (0)

#define RD_A(BUF, QM) do { char* ab_ = ldsA + ((BUF) * 2 + (QM)) * 16384;     \
        _Pragma("unroll") for (int mm = 0; mm < 4; ++mm) {                    \
            afr[mm][0] = *(const f16x8*)(ab_ + rAoff[mm] + c0);               \
            afr[mm][1] = *(const f16x8*)(ab_ + rAoff[mm] + c1); } } while (0)

#define RD_B(BUF, QN, DST) do { char* bb_ = ldsB + ((BUF) * 2 + (QN)) * 16384;\
        _Pragma("unroll") for (int nn = 0; nn < 2; ++nn) {                    \
            DST[nn][0] = *(const f16x8*)(bb_ + rBoff[nn] + c0);               \
            DST[nn][1] = *(const f16x8*)(bb_ + rBoff[nn] + c1); } } while (0)

#define MFMA_Q(QM, QN, BQ)                                                    \
        __builtin_amdgcn_s_setprio(1);                                        \
        _Pragma("unroll") for (int mm = 0; mm < 4; ++mm)                      \
        _Pragma("unroll") for (int nn = 0; nn < 2; ++nn)                      \
        _Pragma("unroll") for (int kk = 0; kk < 2; ++kk)                      \
            acc[(QM)*4+mm][(QN)*2+nn] =                                       \
                __builtin_amdgcn_mfma_f32_16x16x32_f16(                       \
                    afr[mm][kk], BQ[nn][kk], acc[(QM)*4+mm][(QN)*2+nn],0,0,0);\
        __builtin_amdgcn_s_setprio(0);

    // prologue: K0 full -> buf0, K1 {A0,B0,B1} -> buf1 (7 stages, 14 loads).
    STAGE_A(0, 0, 0); STAGE_B(0, 0, 0); STAGE_B(1, 0, 0); STAGE_A(1, 0, 0);
    STAGE_A(0, 1, 1); STAGE_B(0, 1, 1); STAGE_B(1, 1, 1);
    VMW6; BARRIER;

    for (int t = 0; t < NKT; t += 2) {
        const int k2 = (t + 2) & 63;   // t=62 -> dead restage of K0/K1
        const int k3 = (t + 3) & 63;
        // ---- PA: quadrants Q00,Q01 of K-tile t (buf0) ----
        RD_A(0, 0); RD_B(0, 0, blo); RD_B(0, 1, bhi);
        STAGE_A(1, t + 1, 1);
        MFMA_Q(0, 0, blo); MFMA_Q(0, 1, bhi);
        BARRIER;
        // ---- PB: quadrants Q10,Q11 (buf0) ; stage t+2 A0/B0/B1 -> b0 ----
        RD_A(0, 1);
        STAGE_A(0, k2, 0); STAGE_B(0, k2, 0); STAGE_B(1, k2, 0);
        MFMA_Q(1, 0, blo); MFMA_Q(1, 1, bhi);
        VMW6; BARRIER;      // retires buf1 K-tile t+1; barrier publishes
        // ---- PC: quadrants Q00,Q01 of K-tile t+1 (buf1) ----
        RD_A(1, 0); RD_B(1, 0, blo); RD_B(1, 1, bhi);
        STAGE_A(1, k2, 0);
        MFMA_Q(0, 0, blo); MFMA_Q(0, 1, bhi);
        BARRIER;
        // ---- PD: quadrants Q10,Q11 (buf1) ; stage t+3 A0/B0/B1 -> b1 ----
        RD_A(1, 1);
        STAGE_A(0, k3, 1); STAGE_B(0, k3, 1); STAGE_B(1, k3, 1);
        MFMA_Q(1, 0, blo); MFMA_Q(1, 1, bhi);
        VMW6; BARRIER;      // retires buf0 K-tile t+2
    }
    asm volatile("s_waitcnt vmcnt(0)" ::: "memory");   // drain DMA before end

#pragma unroll
    for (int m = 0; m < 8; ++m) {
        const int Mr = bm0 + (m >> 2) * 128 + wm * 64 + (m & 3) * 16 + (lane >> 4) * 4;
#pragma unroll
        for (int n = 0; n < 4; ++n) {
            const int Nc = bn0 + (n >> 1) * 128 + wn * 32 + (n & 1) * 16 + lane15;
#pragma unroll
            for (int r = 0; r < 4; ++r)
                C[(size_t)(Mr + r) * OUT_F + Nc] = acc[m][n][r];
        }
    }
#undef STAGE_A
#undef STAGE_B
#undef RD_A
#undef RD_B
#undef MFMA_Q
}

// ---------------- fallback: m97-structure GEMM (static 16 KB LDS) ----------
__global__ __launch_bounds__(256, 3)
void gemm_f16(const _Float16* __restrict__ A,
              const _Float16* __restrict__ B,
              float*          __restrict__ C)
{
    __shared__ __align__(16) _Float16 lA[128 * 32];
    __shared__ __align__(16) _Float16 lB[128 * 32];

    const int tid  = threadIdx.x;
    const int lane = tid & 63;
    const int bid = blockIdx.x;
    const int swz = (bid & 7) * 128 + (bid >> 3);
    const int bm0 = (swz >> 5) * 128;
    const int bn0 = (swz & 31) * 128;

    const int sr = tid >> 2;
    const int sc = (tid & 3) * 8;
    const _Float16* Aps = A + (size_t)(bm0 + sr) * IN_F + sc;
    const _Float16* Bps = B + (size_t)(bn0 + sr) * IN_F + sc;
    char* lAb = (char*)lA + (tid & ~63) * 16;
    char* lBb = (char*)lB + (tid & ~63) * 16;

    const int wv = tid >> 6;
    const int wr = (wv >> 1) * 64;
    const int wc = (wv & 1)  * 64;
    const int lr  = lane & 15;
    const int lkb = (lane >> 4) * 16;

    f32x4 acc[4][4];
#pragma unroll
    for (int m = 0; m < 4; ++m)
#pragma unroll
        for (int n = 0; n < 4; ++n) acc[m][n] = (f32x4)0.0f;

    for (int kt = 0; kt < 128; ++kt) {
        __syncthreads();
        {
            const _Float16* ak = Aps + kt * 32;
            const _Float16* bk = Bps + kt * 32;
            GLOAD16(ak, lAb);
            GLOAD16(ak + (size_t)64 * IN_F, lAb + 4096);
            GLOAD16(bk, lBb);
            GLOAD16(bk + (size_t)64 * IN_F, lBb + 4096);
        }
        __syncthreads();

        f16x8 a[4], b[4];
#pragma unroll
        for (int m = 0; m < 4; ++m)
            a[m] = *(const f16x8*)((const char*)lA + (wr + m * 16 + lr) * 64 + lkb);
#pragma unroll
        for (int n = 0; n < 4; ++n)
            b[n] = *(const f16x8*)((const char*)lB + (wc + n * 16 + lr) * 64 + lkb);
#pragma unroll
        for (int m = 0; m < 4; ++m)
#pragma unroll
            for (int n = 0; n < 4; ++n)
                acc[m][n] = __builtin_amdgcn_mfma_f32_16x16x32_f16(
                    a[m], b[n], acc[m][n], 0, 0, 0);
    }

    const int crow = bm0 + wr + (lane >> 4) * 4;
    const int ccol = bn0 + wc + lr;
#pragma unroll
    for (int m = 0; m < 4; ++m)
#pragma unroll
        for (int n = 0; n < 4; ++n)
#pragma unroll
            for (int r = 0; r < 4; ++r)
                C[(size_t)(crow + m * 16 + r) * OUT_F + (ccol + n * 16)]
                    = acc[m][n][r];
}

extern "C" void kernel_launch(void* const* d_in, const int* in_sizes, int n_in,
                              void* d_out, int out_size, void* d_ws, size_t ws_size,
                              hipStream_t stream) {
    (void)in_sizes; (void)n_in; (void)out_size; (void)ws_size;
    const float* x  = (const float*)d_in[0];
    const int*   qw = (const int*)d_in[1];
    const float* s  = (const float*)d_in[2];
    float*       out = (float*)d_out;

    _Float16* xf = (_Float16*)d_ws;
    _Float16* wf = xf + (size_t)OUT_F * IN_F;
    prep<<<dim3(16384), dim3(256), 0, stream>>>(x, qw, s, xf, wf);

    hipError_t e = hipFuncSetAttribute((const void*)gemm8p,
        hipFuncAttributeMaxDynamicSharedMemorySize, 131072);
    if (e == hipSuccess)
        gemm8p<<<dim3(256), dim3(512), 131072, stream>>>(xf, wf, out);
    else
        gemm_f16<<<dim3(1024), dim3(256), 0, stream>>>(xf, wf, out);
}